// Round 3
// baseline (69.348 us; speedup 1.0000x reference)
//
#include <hip/hip_runtime.h>

// Degree-4 SH encoding: 12 B in, 64 B out per point. Write-bound streaming.
// Round-1: per-thread 256B output blocks -> 2.4x write amplification. Fixed.
// Round-2: LDS transpose + 2 barriers/round = vmcnt(0) drain before every
// s_barrier throttled store MLP (4.4 TB/s vs fill kernel's 7 TB/s).
// Round-3 fix: barrier-free direct scheme. 4 lanes share one point:
//   lane l -> point p = tile*16 + (l>>2), coefficient group c = l&3
//   store index 4p + c = tile*64 + l  == naturally lane-contiguous 1KB/wave.
// No LDS, no barriers, no shuffles. 4x read replication is broadcast-coalesced
// and L3-resident (FETCH ~25MB).

__global__ __launch_bounds__(256)
void SHEncoder_53077205844617_kernel(const float* __restrict__ in,
                                     float* __restrict__ out,
                                     const int* __restrict__ size_ptr,
                                     int B) {
    const int lane = threadIdx.x & 63;
    const int wid  = blockIdx.x * (blockDim.x >> 6) + (threadIdx.x >> 6);
    const int nw   = gridDim.x * (blockDim.x >> 6);

    const float inv = 1.0f / (float)(*size_ptr);   // uniform
    float4* __restrict__ out4 = (float4*)out;

    const int sub = lane >> 2;   // 0..15 : which point within the wave tile
    const int c   = lane & 3;    // which float4 group of that point
    const int ntiles = (B + 15) >> 4;   // 16 points per wave tile

    for (int tile = wid; tile < ntiles; tile += nw) {
        const int p = tile * 16 + sub;
        float x = 0.f, y = 0.f, z = 0.f;
        if (p < B) {
            x = in[3 * p + 0] * inv;
            y = in[3 * p + 1] * inv;
            z = in[3 * p + 2] * inv;
        }
        const float xx = x * x, yy = y * y, zz = z * z;
        const float xy = x * y, yz = y * z, xz = x * z;

        float4 o;
        switch (c) {
        case 0:
            o.x = 0.28209479177387814f;
            o.y = -0.4886025119029199f * y;
            o.z =  0.4886025119029199f * z;
            o.w = -0.4886025119029199f * x;
            break;
        case 1:
            o.x =  1.0925484305920792f  * xy;
            o.y = -1.0925484305920792f  * yz;
            o.z =  0.31539156525252005f * (2.0f * zz - xx - yy);
            o.w = -1.0925484305920792f  * xz;
            break;
        case 2:
            o.x =  0.5462742152960396f  * (xx - yy);
            o.y = -0.5900435899266435f  * y * (3.0f * xx - yy);
            o.z =  2.890611442640554f   * xy * z;
            o.w = -0.4570457994644658f  * y * (4.0f * zz - xx - yy);
            break;
        default:
            o.x =  0.3731763325901154f  * z * (2.0f * zz - 3.0f * xx - 3.0f * yy);
            o.y = -0.4570457994644658f  * x * (4.0f * zz - xx - yy);
            o.z =  1.445305721320277f   * z * (xx - yy);
            o.w = -0.5900435899266435f  * x * (xx - 3.0f * yy);
            break;
        }

        const int qg = tile * 64 + lane;     // float4 index; == 4p + c
        if (qg < 4 * B) out4[qg] = o;
    }
}

extern "C" void kernel_launch(void* const* d_in, const int* in_sizes, int n_in,
                              void* d_out, int out_size, void* d_ws, size_t ws_size,
                              hipStream_t stream) {
    const float* in       = (const float*)d_in[0];
    const int*   size_ptr = (const int*)d_in[1];
    float*       out      = (float*)d_out;

    const int B = in_sizes[0] / 3;

    // Memory-bound: cap grid and grid-stride (G11). 2048 blocks x 4 waves
    // = 8192 waves, 32 tiles each at B = 4M.
    const int threads = 256;
    const int ntiles  = (B + 15) >> 4;
    const int waves_needed = ntiles;                    // 1 tile min per wave
    int blocks = (waves_needed + 3) / 4;                // 4 waves per block
    if (blocks > 2048) blocks = 2048;
    if (blocks < 1) blocks = 1;

    SHEncoder_53077205844617_kernel<<<blocks, threads, 0, stream>>>(in, out, size_ptr, B);
}

// Round 5
// 55.231 us; speedup vs baseline: 1.2556x; 1.2556x over previous
//
#include <hip/hip_runtime.h>

// Degree-4 SH encoding: 12 B in, 64 B out per point. Write-bound streaming.
// R1: per-thread 256B blocks -> 2.4x write amplification (WRITE 650MB). Fixed R2.
// R2: LDS transpose, 1KB/wave lane-contiguous stores -> 67.7us (4.3 TB/s).
// R3: barrier-free direct (4 lanes/point, store idx tile*64+lane) -> 69.3us.
//     Barrier-drain theory dead: two structures, same plateau.
// R4: nontemporal stores (output 268MB ~ L3 256MB; bypass write-allocate) +
//     2-tile unroll. R4 compile fix: __builtin_nontemporal_store needs a
//     NATIVE clang vector type, not HIP_vector_type -> use ext_vector_type.

typedef float f32x4 __attribute__((ext_vector_type(4)));

__device__ __forceinline__ f32x4 sh_group(int c, float x, float y, float z) {
    const float xx = x * x, yy = y * y, zz = z * z;
    const float xy = x * y, yz = y * z, xz = x * z;
    f32x4 o;
    switch (c) {
    case 0:
        o.x = 0.28209479177387814f;
        o.y = -0.4886025119029199f * y;
        o.z =  0.4886025119029199f * z;
        o.w = -0.4886025119029199f * x;
        break;
    case 1:
        o.x =  1.0925484305920792f  * xy;
        o.y = -1.0925484305920792f  * yz;
        o.z =  0.31539156525252005f * (2.0f * zz - xx - yy);
        o.w = -1.0925484305920792f  * xz;
        break;
    case 2:
        o.x =  0.5462742152960396f  * (xx - yy);
        o.y = -0.5900435899266435f  * y * (3.0f * xx - yy);
        o.z =  2.890611442640554f   * xy * z;
        o.w = -0.4570457994644658f  * y * (4.0f * zz - xx - yy);
        break;
    default:
        o.x =  0.3731763325901154f  * z * (2.0f * zz - 3.0f * xx - 3.0f * yy);
        o.y = -0.4570457994644658f  * x * (4.0f * zz - xx - yy);
        o.z =  1.445305721320277f   * z * (xx - yy);
        o.w = -0.5900435899266435f  * x * (xx - 3.0f * yy);
        break;
    }
    return o;
}

__global__ __launch_bounds__(256)
void SHEncoder_53077205844617_kernel(const float* __restrict__ in,
                                     float* __restrict__ out,
                                     const int* __restrict__ size_ptr,
                                     int B) {
    const int lane = threadIdx.x & 63;
    const int wid  = blockIdx.x * (blockDim.x >> 6) + (threadIdx.x >> 6);
    const int nw   = gridDim.x * (blockDim.x >> 6);

    const float inv = 1.0f / (float)(*size_ptr);
    f32x4* __restrict__ out4 = (f32x4*)out;

    const int sub = lane >> 2;          // point within wave tile (0..15)
    const int c   = lane & 3;           // float4 group of that point
    const int ntiles = (B + 15) >> 4;   // 16 points per wave tile
    const int qlim   = 4 * B;

    for (int t0 = wid; t0 < ntiles; t0 += 2 * nw) {
        const int tA = t0;
        const int tB = t0 + nw;
        const bool hasB = (tB < ntiles);

        // Issue both tiles' loads up front (independent chains -> MLP).
        float xA = 0.f, yA = 0.f, zA = 0.f;
        float xB = 0.f, yB = 0.f, zB = 0.f;
        const int pA = tA * 16 + sub;
        const int pB = tB * 16 + sub;
        if (pA < B) {
            xA = in[3 * pA + 0]; yA = in[3 * pA + 1]; zA = in[3 * pA + 2];
        }
        if (hasB && pB < B) {
            xB = in[3 * pB + 0]; yB = in[3 * pB + 1]; zB = in[3 * pB + 2];
        }

        const f32x4 oA = sh_group(c, xA * inv, yA * inv, zA * inv);
        const f32x4 oB = sh_group(c, xB * inv, yB * inv, zB * inv);

        const int qA = tA * 64 + lane;       // == 4*pA + c
        if (qA < qlim) __builtin_nontemporal_store(oA, &out4[qA]);
        if (hasB) {
            const int qB = tB * 64 + lane;
            if (qB < qlim) __builtin_nontemporal_store(oB, &out4[qB]);
        }
    }
}

extern "C" void kernel_launch(void* const* d_in, const int* in_sizes, int n_in,
                              void* d_out, int out_size, void* d_ws, size_t ws_size,
                              hipStream_t stream) {
    const float* in       = (const float*)d_in[0];
    const int*   size_ptr = (const int*)d_in[1];
    float*       out      = (float*)d_out;

    const int B = in_sizes[0] / 3;

    const int threads = 256;
    const int ntiles  = (B + 15) >> 4;
    int blocks = (ntiles + 3) / 4;       // 4 waves/block, 1 tile/wave min
    if (blocks > 2048) blocks = 2048;
    if (blocks < 1) blocks = 1;

    SHEncoder_53077205844617_kernel<<<blocks, threads, 0, stream>>>(in, out, size_ptr, B);
}